// Round 4
// baseline (3411.255 us; speedup 1.0000x reference)
//
#include <hip/hip_runtime.h>

#define TT 256
#define CONDL 192
#define PREDL 64
#define HH 256
#define BB 4096
#define BT 16            // batch tile per block
#define HPAD 264         // h row stride in bf16 elems (16B-aligned rows)
#define HBUF (BT * HPAD)
#define NTHR 512         // 8 waves, 2 per SIMD

typedef short bf16x8 __attribute__((ext_vector_type(8)));
typedef float f32x4 __attribute__((ext_vector_type(4)));
typedef unsigned short u16x4 __attribute__((ext_vector_type(4)));

__device__ __forceinline__ short f2bf(float f) {
  unsigned u = __builtin_bit_cast(unsigned, f);
  unsigned r = (u + 0x7fffu + ((u >> 16) & 1u)) >> 16;
  return (short)r;
}
__device__ __forceinline__ float bf2f(short s) {
  unsigned u = ((unsigned)(unsigned short)s) << 16;
  return __builtin_bit_cast(float, u);
}
__device__ __forceinline__ float bflo(unsigned p) {
  return __builtin_bit_cast(float, p << 16);
}
__device__ __forceinline__ float bfhi(unsigned p) {
  return __builtin_bit_cast(float, p & 0xffff0000u);
}
__device__ __forceinline__ float sig_(float x) {
  return __builtin_amdgcn_rcpf(1.0f + __builtin_amdgcn_exp2f(-1.44269504f * x));
}
__device__ __forceinline__ float tanh_(float x) {
  float e = __builtin_amdgcn_exp2f(2.88539008f * x);  // exp(2x)
  return 1.0f - 2.0f * __builtin_amdgcn_rcpf(e + 1.0f);
}

// Pack w_hh [1024][256] fp32 -> bf16 B-fragments in exact MFMA operand order:
// frag (jt,kt): lane holds W[n = jt*16 + (lane&15)][k = kt*32 + (lane>>4)*8 + 0..7]
__global__ void pack_w(const float* __restrict__ w_hh, short* __restrict__ wp) {
  int idx = blockIdx.x * 256 + threadIdx.x;   // 64 jt * 8 kt * 64 lanes
  int lane = idx & 63;
  int kt = (idx >> 6) & 7;
  int jt = idx >> 9;
  int n = jt * 16 + (lane & 15);
  int k0 = kt * 32 + (lane >> 4) * 8;
  bf16x8 v;
#pragma unroll
  for (int j = 0; j < 8; ++j) v[j] = f2bf(w_hh[n * 256 + k0 + j]);
  *(bf16x8*)(wp + (long)idx * 8) = v;
}

__global__ __launch_bounds__(NTHR, 2)
void lstm_main(const float* __restrict__ cd, const float* __restrict__ pred,
               const float* __restrict__ w_ih, const float* __restrict__ b_ih,
               const float* __restrict__ b_hh, const float* __restrict__ w_out,
               const float* __restrict__ b_out, const short* __restrict__ wp,
               float* __restrict__ out) {
  // LDS: weights 128 KB (o-gate, 16 tiles) + h dbuf 16.5 KB + x 8 KB + flags
  __shared__ __align__(16) short lds_w[16 * 8 * 64 * 8];
  __shared__ __align__(16) short h_s[2 * HBUF];
  __shared__ __align__(16) short x_s[TT * BT];
  __shared__ unsigned flags_s[8];   // per-wave completed-steps counter

  const int tid = threadIdx.x;
  const int lane = tid & 63;
  const int wv = tid >> 6;        // wave 0..7
  const int r0 = blockIdx.x * BT;
  const int lm = lane & 15;
  const int lq = lane >> 4;
  const int m0 = lq * 4;

  const bf16x8* wpf = (const bf16x8*)wp;
  bf16x8* ldsw = (bf16x8*)lds_w;

  // ---- one-time staging ----
  for (int i = tid; i < BT * CONDL; i += NTHR) {
    int r = i / CONDL, t = i % CONDL;
    x_s[t * BT + r] = f2bf(cd[(r0 + r) * CONDL + t]);
  }
  for (int i = tid; i < BT * PREDL; i += NTHR) {
    int r = i / PREDL, t = i % PREDL;
    x_s[(CONDL + t) * BT + r] = f2bf(pred[(r0 + r) * PREDL + t]);
  }
  for (int i = tid; i < HBUF; i += NTHR) h_s[i] = 0;  // h_0 = 0, buffer 0
  if (tid < 8) flags_s[tid] = 0;

  // wave wv owns unit-subtiles wv*2 + {0,1}; jt = g*16 + subtile.
  // g in {0,1,2} (i,f,g) -> VGPR; g == 3 (o) -> LDS tile at ((wv*2+i)*8+kt)*64+lane.
#pragma unroll
  for (int i = 0; i < 2; ++i) {
    int st = wv * 2 + i;
#pragma unroll
    for (int kt = 0; kt < 8; ++kt)
      ldsw[(st * 8 + kt) * 64 + lane] = wpf[((48 + st) * 8 + kt) * 64 + lane];
  }

  // VGPR-resident tiles: 6 per wave (a = g*2+i, g<3) = 48 frags = 192 regs
  bf16x8 wreg[48];
#pragma unroll
  for (int a = 0; a < 6; ++a) {
    int jt = (a >> 1) * 16 + wv * 2 + (a & 1);
#pragma unroll
    for (int kt = 0; kt < 8; ++kt)
      wreg[a * 8 + kt] = wpf[(jt * 8 + kt) * 64 + lane];
  }
#pragma unroll
  for (int i = 0; i < 48; ++i) asm volatile("" : "+v"(wreg[i]));

  // packed (w_ih, b_ih+b_hh) bf16 pairs; a = g*2+i
  unsigned wbs[8];
#pragma unroll
  for (int a = 0; a < 8; ++a) {
    int j = (a >> 1) * 256 + (wv * 2 + (a & 1)) * 16 + lm;
    unsigned lo = (unsigned short)f2bf(w_ih[j]);
    unsigned hi = (unsigned short)f2bf(b_ih[j] + b_hh[j]);
    wbs[a] = lo | (hi << 16);
  }

  float cst[8];
#pragma unroll
  for (int i = 0; i < 8; ++i) cst[i] = 0.f;

  f32x4 zero4;
  zero4[0] = 0.f; zero4[1] = 0.f; zero4[2] = 0.f; zero4[3] = 0.f;

  __syncthreads();

  // ---- recurrence: no block barrier; per-wave flag sync ----
  // af[kt] (k in [kt*32, kt*32+32)) is produced entirely by wave kt, so
  // consuming step t only needs flags_s[kt] >= t (wave kt completed t steps).
  // Writes of step t happen only after all flags >= t were observed -> the
  // 2-buffer WAR hazard (step t writes alias step t-1 reads) cannot occur.
#pragma unroll 1
  for (int t = 0; t < TT; ++t) {
    const short* hr = h_s + (t & 1) * HBUF;
    short* hw = h_s + ((t + 1) & 1) * HBUF;

    f32x4 acc[8];   // a = g*2+i: 0,1=i; 2,3=f; 4,5=g; 6,7=o
    // own tile first: no flag wait, h just written by this wave
    bf16x8 af_cur = *(const bf16x8*)(hr + lm * HPAD + wv * 32 + lq * 8);

#pragma unroll
    for (int j = 0; j < 8; ++j) {
      int kt = (wv + j) & 7;
      bf16x8 af_nxt;
      if (j < 7) {
        int ktn = (wv + j + 1) & 7;
        while (__hip_atomic_load(&flags_s[ktn], __ATOMIC_ACQUIRE,
                                 __HIP_MEMORY_SCOPE_WORKGROUP) < (unsigned)t) {}
        af_nxt = *(const bf16x8*)(hr + lm * HPAD + ktn * 32 + lq * 8);
      }
      bf16x8 o0 = ldsw[((wv * 2 + 0) * 8 + kt) * 64 + lane];
      bf16x8 o1 = ldsw[((wv * 2 + 1) * 8 + kt) * 64 + lane];
#pragma unroll
      for (int a = 0; a < 6; ++a)
        acc[a] = __builtin_amdgcn_mfma_f32_16x16x32_bf16(
            af_cur, wreg[a * 8 + kt], (j == 0) ? zero4 : acc[a], 0, 0, 0);
      acc[6] = __builtin_amdgcn_mfma_f32_16x16x32_bf16(
          af_cur, o0, (j == 0) ? zero4 : acc[6], 0, 0, 0);
      acc[7] = __builtin_amdgcn_mfma_f32_16x16x32_bf16(
          af_cur, o1, (j == 0) ? zero4 : acc[7], 0, 0, 0);
      af_cur = af_nxt;
    }

    // x_t for this lane's 4 batch rows
    u16x4 xq = *(const u16x4*)(x_s + t * BT + m0);
    float xr[4];
#pragma unroll
    for (int v = 0; v < 4; ++v) xr[v] = bf2f((short)xq[v]);

    // LSTM elementwise; unit u = (wv*2+i)*16 + lm
#pragma unroll
    for (int i = 0; i < 2; ++i) {
      int u = (wv * 2 + i) * 16 + lm;
      float wI = bflo(wbs[i]),     bI = bfhi(wbs[i]);
      float wF = bflo(wbs[2 + i]), bF = bfhi(wbs[2 + i]);
      float wG = bflo(wbs[4 + i]), bG = bfhi(wbs[4 + i]);
      float wO = bflo(wbs[6 + i]), bO = bfhi(wbs[6 + i]);
#pragma unroll
      for (int v = 0; v < 4; ++v) {
        float ig = sig_(acc[i][v]     + xr[v] * wI + bI);
        float fg = sig_(acc[2 + i][v] + xr[v] * wF + bF);
        float gg = tanh_(acc[4 + i][v] + xr[v] * wG + bG);
        float og = sig_(acc[6 + i][v] + xr[v] * wO + bO);
        float cn = fg * cst[i * 4 + v] + ig * gg;
        cst[i * 4 + v] = cn;
        hw[(m0 + v) * HPAD + u] = f2bf(og * tanh_(cn));
      }
    }
    // publish: release orders all h-writes (wave-level waitcnt) before flag
    if (lane == 0)
      __hip_atomic_store(&flags_s[wv], (unsigned)(t + 1), __ATOMIC_RELEASE,
                         __HIP_MEMORY_SCOPE_WORKGROUP);
  }

  __syncthreads();

  // ---- readout: out[r] = sigmoid(h_last . w_out + b_out); buffer 0 (T even) ----
  const short* hf = h_s;
  float bo = b_out[0];
#pragma unroll
  for (int rr = 0; rr < 2; ++rr) {
    int row = wv * 2 + rr;
    float p = 0.f;
#pragma unroll
    for (int c = 0; c < 4; ++c) {
      int k = lane + c * 64;
      p += bf2f(hf[row * HPAD + k]) * w_out[k];
    }
#pragma unroll
    for (int off = 32; off > 0; off >>= 1) p += __shfl_down(p, off);
    if (lane == 0) out[r0 + row] = sig_(p + bo);
  }
}

extern "C" void kernel_launch(void* const* d_in, const int* in_sizes, int n_in,
                              void* d_out, int out_size, void* d_ws, size_t ws_size,
                              hipStream_t stream) {
  const float* cd    = (const float*)d_in[0];
  const float* pr    = (const float*)d_in[1];
  const float* w_ih  = (const float*)d_in[2];
  const float* w_hh  = (const float*)d_in[3];
  const float* b_ih  = (const float*)d_in[4];
  const float* b_hh  = (const float*)d_in[5];
  const float* w_out = (const float*)d_in[6];
  const float* b_out = (const float*)d_in[7];
  float* out = (float*)d_out;
  short* wp = (short*)d_ws;   // 512 KB packed bf16 weights

  pack_w<<<128, 256, 0, stream>>>(w_hh, wp);
  lstm_main<<<256, NTHR, 0, stream>>>(cd, pr, w_ih, b_ih, b_hh, w_out, b_out, wp, out);
}

// Round 5
// 768.502 us; speedup vs baseline: 4.4388x; 4.4388x over previous
//
#include <hip/hip_runtime.h>

#define TT 256
#define CONDL 192
#define PREDL 64
#define HH 256
#define BB 4096
#define BT 16            // batch tile per block
#define HPAD 264         // h row stride in bf16 elems
#define HBUF (BT * HPAD)
#define NTHR 512         // 8 waves, 2 per SIMD

typedef short bf16x8 __attribute__((ext_vector_type(8)));
typedef float f32x4 __attribute__((ext_vector_type(4)));
typedef unsigned short u16x4 __attribute__((ext_vector_type(4)));

__device__ __forceinline__ short f2bf(float f) {
  unsigned u = __builtin_bit_cast(unsigned, f);
  unsigned r = (u + 0x7fffu + ((u >> 16) & 1u)) >> 16;
  return (short)r;
}
__device__ __forceinline__ float bf2f(short s) {
  unsigned u = ((unsigned)(unsigned short)s) << 16;
  return __builtin_bit_cast(float, u);
}
__device__ __forceinline__ float bflo(unsigned p) {
  return __builtin_bit_cast(float, p << 16);
}
__device__ __forceinline__ float bfhi(unsigned p) {
  return __builtin_bit_cast(float, p & 0xffff0000u);
}
__device__ __forceinline__ float sig_(float x) {
  return __builtin_amdgcn_rcpf(1.0f + __builtin_amdgcn_exp2f(-1.44269504f * x));
}
__device__ __forceinline__ float tanh_(float x) {
  float e = __builtin_amdgcn_exp2f(2.88539008f * x);  // exp(2x)
  return 1.0f - 2.0f * __builtin_amdgcn_rcpf(e + 1.0f);
}

// Pack w_hh [1024][256] fp32 -> bf16 B-fragments in exact MFMA operand order:
// frag (jt,kt): lane holds W[n = jt*16 + (lane&15)][k = kt*32 + (lane>>4)*8 + 0..7]
__global__ void pack_w(const float* __restrict__ w_hh, short* __restrict__ wp) {
  int idx = blockIdx.x * 256 + threadIdx.x;   // 64 jt * 8 kt * 64 lanes
  int lane = idx & 63;
  int kt = (idx >> 6) & 7;
  int jt = idx >> 9;
  int n = jt * 16 + (lane & 15);
  int k0 = kt * 32 + (lane >> 4) * 8;
  bf16x8 v;
#pragma unroll
  for (int j = 0; j < 8; ++j) v[j] = f2bf(w_hh[n * 256 + k0 + j]);
  *(bf16x8*)(wp + (long)idx * 8) = v;
}

__global__ __launch_bounds__(NTHR, 2)
void lstm_main(const float* __restrict__ cd, const float* __restrict__ pred,
               const float* __restrict__ w_ih, const float* __restrict__ b_ih,
               const float* __restrict__ b_hh, const float* __restrict__ w_out,
               const float* __restrict__ b_out, const short* __restrict__ wp,
               float* __restrict__ out) {
  // LDS: weights 128 KB (o-gate, 16 tiles) + h dbuf 16.9 KB + x 8 KB = 152.9 KB
  __shared__ __align__(16) short lds_w[16 * 8 * 64 * 8];
  __shared__ __align__(16) short h_s[2 * HBUF];
  __shared__ __align__(16) short x_s[TT * BT];

  const int tid = threadIdx.x;
  const int lane = tid & 63;
  const int wv = tid >> 6;        // wave 0..7
  const int r0 = blockIdx.x * BT;
  const int lm = lane & 15;
  const int lq = lane >> 4;
  const int m0 = lq * 4;

  const bf16x8* wpf = (const bf16x8*)wp;
  bf16x8* ldsw = (bf16x8*)lds_w;

  // ---- one-time staging ----
  for (int i = tid; i < BT * CONDL; i += NTHR) {
    int r = i / CONDL, t = i % CONDL;
    x_s[t * BT + r] = f2bf(cd[(r0 + r) * CONDL + t]);
  }
  for (int i = tid; i < BT * PREDL; i += NTHR) {
    int r = i / PREDL, t = i % PREDL;
    x_s[(CONDL + t) * BT + r] = f2bf(pred[(r0 + r) * PREDL + t]);
  }
  for (int i = tid; i < HBUF; i += NTHR) h_s[i] = 0;  // h_0 = 0, buffer 0

  // wave wv owns unit-subtiles wv*2 + {0,1}; a = g*2+i, jt(a) = (a>>1)*16 + wv*2 + (a&1)
  // residency: a in {0,1,2} -> VGPR (96 regs); {3,4,5} -> streamed from L2
  //            (2-deep prefetch, constant addresses); {6,7} (o-gate) -> LDS.
#pragma unroll
  for (int i = 0; i < 2; ++i) {
    int st = wv * 2 + i;
#pragma unroll
    for (int kt = 0; kt < 8; ++kt)
      ldsw[(st * 8 + kt) * 64 + lane] = wpf[((48 + st) * 8 + kt) * 64 + lane];
  }

  // VGPR-resident: 3 tiles/wave = 24 frags = 96 regs (low pressure -> stays live)
  bf16x8 wreg[24];
#pragma unroll
  for (int a = 0; a < 3; ++a) {
    int jt = (a >> 1) * 16 + wv * 2 + (a & 1);
#pragma unroll
    for (int kt = 0; kt < 8; ++kt)
      wreg[a * 8 + kt] = wpf[(jt * 8 + kt) * 64 + lane];
  }
#pragma unroll
  for (int i = 0; i < 24; ++i) asm volatile("" : "+v"(wreg[i]));

  // streamed-tile base pointers (values identical every step)
  const bf16x8* sbase0 = wpf + ((16 + wv * 2 + 1) * 8) * 64 + lane;  // a=3 (f,i=1)
  const bf16x8* sbase1 = wpf + ((32 + wv * 2) * 8) * 64 + lane;      // a=4 (g,i=0)
  const bf16x8* sbase2 = wpf + ((32 + wv * 2 + 1) * 8) * 64 + lane;  // a=5 (g,i=1)

  // packed (w_ih, b_ih+b_hh) bf16 pairs; a = g*2+i
  unsigned wbs[8];
#pragma unroll
  for (int a = 0; a < 8; ++a) {
    int j = (a >> 1) * 256 + (wv * 2 + (a & 1)) * 16 + lm;
    unsigned lo = (unsigned short)f2bf(w_ih[j]);
    unsigned hi = (unsigned short)f2bf(b_ih[j] + b_hh[j]);
    wbs[a] = lo | (hi << 16);
  }

  float cst[8];
#pragma unroll
  for (int i = 0; i < 8; ++i) cst[i] = 0.f;

  f32x4 zero4;
  zero4[0] = 0.f; zero4[1] = 0.f; zero4[2] = 0.f; zero4[3] = 0.f;

  // prologue prefetch: kt=0 -> slot0, kt=1 -> slot1 (slot = kt % 3)
  bf16x8 sfr[3][3];
  sfr[0][0] = sbase0[0];       sfr[0][1] = sbase1[0];       sfr[0][2] = sbase2[0];
  sfr[1][0] = sbase0[64];      sfr[1][1] = sbase1[64];      sfr[1][2] = sbase2[64];

  __syncthreads();

  // ---- recurrence ----
  for (int t = 0; t < TT; ++t) {
    const short* hr = h_s + (t & 1) * HBUF;
    short* hw = h_s + ((t + 1) & 1) * HBUF;

    f32x4 acc[8];   // a = g*2+i: 0,1=i; 2,3=f; 4,5=g; 6,7=o
#pragma unroll
    for (int kt = 0; kt < 8; ++kt) {
      // prefetch streamed frags for kt+2 (distance 2 hides L2 latency)
      if (kt < 6) {
        int s = (kt + 2) % 3;
        sfr[s][0] = sbase0[(kt + 2) * 64];
        sfr[s][1] = sbase1[(kt + 2) * 64];
        sfr[s][2] = sbase2[(kt + 2) * 64];
      }
      bf16x8 af = *(const bf16x8*)(hr + lm * HPAD + kt * 32 + lq * 8);
      int sc = kt % 3;
#pragma unroll
      for (int a = 0; a < 3; ++a)
        acc[a] = __builtin_amdgcn_mfma_f32_16x16x32_bf16(
            af, wreg[a * 8 + kt], (kt == 0) ? zero4 : acc[a], 0, 0, 0);
#pragma unroll
      for (int s = 0; s < 3; ++s)
        acc[3 + s] = __builtin_amdgcn_mfma_f32_16x16x32_bf16(
            af, sfr[sc][s], (kt == 0) ? zero4 : acc[3 + s], 0, 0, 0);
#pragma unroll
      for (int i = 0; i < 2; ++i)
        acc[6 + i] = __builtin_amdgcn_mfma_f32_16x16x32_bf16(
            af, ldsw[((wv * 2 + i) * 8 + kt) * 64 + lane],
            (kt == 0) ? zero4 : acc[6 + i], 0, 0, 0);
    }

    // x_t for this lane's 4 batch rows
    u16x4 xq = *(const u16x4*)(x_s + t * BT + m0);
    float xr[4];
#pragma unroll
    for (int v = 0; v < 4; ++v) xr[v] = bf2f((short)xq[v]);

    // LSTM elementwise; unit u = (wv*2+i)*16 + lm
#pragma unroll
    for (int i = 0; i < 2; ++i) {
      int u = (wv * 2 + i) * 16 + lm;
      float wI = bflo(wbs[i]),     bI = bfhi(wbs[i]);
      float wF = bflo(wbs[2 + i]), bF = bfhi(wbs[2 + i]);
      float wG = bflo(wbs[4 + i]), bG = bfhi(wbs[4 + i]);
      float wO = bflo(wbs[6 + i]), bO = bfhi(wbs[6 + i]);
#pragma unroll
      for (int v = 0; v < 4; ++v) {
        float ig = sig_(acc[i][v]     + xr[v] * wI + bI);
        float fg = sig_(acc[2 + i][v] + xr[v] * wF + bF);
        float gg = tanh_(acc[4 + i][v] + xr[v] * wG + bG);
        float og = sig_(acc[6 + i][v] + xr[v] * wO + bO);
        float cn = fg * cst[i * 4 + v] + ig * gg;
        cst[i * 4 + v] = cn;
        hw[(m0 + v) * HPAD + u] = f2bf(og * tanh_(cn));
      }
    }

    // re-prime slots 0,1 for next step's kt=0,1 (same addresses; in flight
    // across the barrier -> fully hidden)
    sfr[0][0] = sbase0[0];   sfr[0][1] = sbase1[0];   sfr[0][2] = sbase2[0];
    sfr[1][0] = sbase0[64];  sfr[1][1] = sbase1[64];  sfr[1][2] = sbase2[64];

    __syncthreads();
  }

  // ---- readout: out[r] = sigmoid(h_last . w_out + b_out); buffer 0 (T even) ----
  const short* hf = h_s;
  float bo = b_out[0];
#pragma unroll
  for (int rr = 0; rr < 2; ++rr) {
    int row = wv * 2 + rr;
    float p = 0.f;
#pragma unroll
    for (int c = 0; c < 4; ++c) {
      int k = lane + c * 64;
      p += bf2f(hf[row * HPAD + k]) * w_out[k];
    }
#pragma unroll
    for (int off = 32; off > 0; off >>= 1) p += __shfl_down(p, off);
    if (lane == 0) out[r0 + row] = sig_(p + bo);
  }
}

extern "C" void kernel_launch(void* const* d_in, const int* in_sizes, int n_in,
                              void* d_out, int out_size, void* d_ws, size_t ws_size,
                              hipStream_t stream) {
  const float* cd    = (const float*)d_in[0];
  const float* pr    = (const float*)d_in[1];
  const float* w_ih  = (const float*)d_in[2];
  const float* w_hh  = (const float*)d_in[3];
  const float* b_ih  = (const float*)d_in[4];
  const float* b_hh  = (const float*)d_in[5];
  const float* w_out = (const float*)d_in[6];
  const float* b_out = (const float*)d_in[7];
  float* out = (float*)d_out;
  short* wp = (short*)d_ws;   // 512 KB packed bf16 weights

  pack_w<<<128, 256, 0, stream>>>(w_hh, wp);
  lstm_main<<<256, NTHR, 0, stream>>>(cd, pr, w_ih, b_ih, b_hh, w_out, b_out, wp, out);
}